// Round 2
// baseline (555.584 us; speedup 1.0000x reference)
//
#include <hip/hip_runtime.h>
#include <math.h>
#include <string.h>

#define SEQ 8192
#define DIM 1024
#define NBATCH 8

struct SDesc {
  int n, Tmax, totalRows;
  int pos[8], A[8], rowbase[8];
  int anc[8][8];
  float cnt[8][8];
};

// Host-side faithful reimplementation of _gen_spine/_analyze/_structures,
// including the levels[lvl+1] OVERWRITE semantics of the reference BFS.
static SDesc build_structs() {
  SDesc H{};
  int spine[24];
  int ns = 3; spine[0] = 0; spine[1] = 2; spine[2] = 4;
  for (;;) {
    long nxt = 2L * (spine[ns-1] + spine[ns-2] + spine[ns-3]);
    if (nxt >= SEQ) break;
    spine[ns++] = (int)nxt;
  }
  int rb = 0;
  for (int i = 0; i < ns; ++i) {
    int pos = spine[i];
    if (pos < 3) continue;
    bool visited[24] = {false};
    int levels[12][8]; int lcnt[12];
    for (int l = 0; l < 12; ++l) lcnt[l] = 0;
    levels[0][0] = i; lcnt[0] = 1; visited[i] = true;
    int qidx[64], qlvl[64], qh = 0, qt = 0;
    qidx[qt] = i; qlvl[qt] = 0; qt++;
    int maxd = 0;
    while (qh < qt) {
      int cur = qidx[qh], lvl = qlvl[qh]; qh++;
      if (lvl >= 9) break;
      int newl[8], nn = 0;
      if (cur >= 3) {
        for (int d = 1; d <= 3; ++d) {
          int a = cur - d;
          if (!visited[a]) { visited[a] = true; newl[nn++] = a; qidx[qt] = a; qlvl[qt] = lvl + 1; qt++; }
        }
      }
      if (nn) {
        lcnt[lvl+1] = nn;
        for (int k = 0; k < nn; ++k) levels[lvl+1][k] = newl[k];
        if (lvl + 1 > maxd) maxd = lvl + 1;
      }
    }
    float pcv[24]; bool pcs[24];
    for (int k = 0; k < 24; ++k) { pcv[k] = 0.f; pcs[k] = false; }
    pcv[i] = 1.f; pcs[i] = true;
    for (int lvl = maxd; lvl >= 0; --lvl) {
      for (int nidx = 0; nidx < lcnt[lvl]; ++nidx) {
        int node = levels[lvl][nidx];
        if (node == i) continue;
        if (lvl == maxd) { pcv[node] = 1.f; pcs[node] = true; continue; }
        float c = 0.f;
        for (int cidx = 0; cidx < lcnt[lvl+1]; ++cidx) {
          int ch = levels[lvl+1][cidx];
          if (ch >= 3 && node >= ch - 3 && node <= ch - 1) c += pcs[ch] ? pcv[ch] : 0.f;
        }
        if (lvl != 0) { pcv[node] = c; pcs[node] = true; }
      }
    }
    int A = 0;
    int sidx = H.n;
    for (int lvl = 1; lvl <= maxd; ++lvl) {
      for (int nidx = 0; nidx < lcnt[lvl]; ++nidx) {
        int node = levels[lvl][nidx];
        H.anc[sidx][A] = spine[node];
        H.cnt[sidx][A] = pcs[node] ? pcv[node] : 1.f;
        A++;
      }
    }
    if (A == 0) continue;
    H.pos[sidx] = pos; H.A[sidx] = A; H.rowbase[sidx] = rb; rb += A;
    H.n++;
  }
  H.totalRows = rb;
  H.Tmax = 0;
  for (int s = 0; s < H.n; ++s) if (H.A[s] > H.Tmax) H.Tmax = H.A[s];
  return H;
}

// ---------------- kernels ----------------

// grid-strided contiguous copy slice handled by NC dedicated blocks
__device__ __forceinline__ void do_copy(const float4* __restrict__ src,
                                        float4* __restrict__ dst,
                                        int q, int nc, int start4, int n4) {
  for (int i = q * 256 + threadIdx.x; i < n4; i += nc * 256)
    dst[start4 + i] = src[start4 + i];
}

// block 0: path-weight scalars; blocks 1..: zero GRU h double-buffer
__global__ void k_prepzero(SDesc sd, const float* __restrict__ w1, const float* __restrict__ b1,
                           const float* __restrict__ w2, const float* __restrict__ b2,
                           float* __restrict__ wout, float4* __restrict__ hz, int nzero4) {
  if (blockIdx.x == 0) {
    int t = threadIdx.x;
    int s = t >> 3, a = t & 7;
    if (t < 64 && s < sd.n && a < sd.A[s]) {
      float v = sd.cnt[s][a];
      float acc = 0.f;
      for (int i = 0; i < 64; ++i) {
        float h = v * w1[i] + b1[i];
        if (h > 0.f) acc += h * w2[i];
      }
      float o = acc + b2[0];
      float sp = (o > 0.f) ? (o + log1pf(expf(-o))) : log1pf(expf(o));
      wout[s * 8 + a] = sp;
    }
  } else {
    int base = (blockIdx.x - 1) * 512 + threadIdx.x;
    if (base < nzero4)       hz[base]       = make_float4(0.f, 0.f, 0.f, 0.f);
    if (base + 256 < nzero4) hz[base + 256] = make_float4(0.f, 0.f, 0.f, 0.f);
  }
}

// msg matmul. main blocks: 64 j-tiles x Y row-tiles (4 rows). XCD swizzle: all
// row-tiles of a j-tile land on one XCD so msg_w slice stays L2-resident.
__global__ __launch_bounds__(256) void k_msg(SDesc sd, const float* __restrict__ x,
    const float* __restrict__ msg_w, const float* __restrict__ msg_b,
    float* __restrict__ mraw, int Y, int NC,
    const float4* __restrict__ csrc, float4* __restrict__ cdst, int cstart, int cn) {
  int p = blockIdx.x;
  int NMAIN = 64 * Y;
  if (p >= NMAIN) { do_copy(csrc, cdst, p - NMAIN, NC, cstart, cn); return; }
  int jt  = (p & 7) + 8 * (p / (8 * Y));   // 0..63, constant XCD per jt
  int rt  = ((p >> 3) % Y) * 4;            // row-tile base

  __shared__ float lin[4][2048];
  for (int idx = threadIdx.x; idx < 4 * 512; idx += 256) {
    int r = idx >> 9, c = idx & 511;
    int row = rt + r;
    int rr = row >> 3, b = row & 7;
    int s = 0; while (s + 1 < sd.n && sd.rowbase[s + 1] <= rr) ++s;
    int a = rr - sd.rowbase[s];
    float4 v;
    if (c < 256) v = ((const float4*)(x + ((size_t)b * SEQ + sd.anc[s][a]) * DIM))[c];
    else         v = ((const float4*)(x + ((size_t)b * SEQ + sd.pos[s]) * DIM))[c - 256];
    ((float4*)lin[r])[c] = v;
  }
  __syncthreads();
  int wave = threadIdx.x >> 6, lane = threadIdx.x & 63;
  int jbase = jt * 16 + wave * 4;
  for (int jj = 0; jj < 4; ++jj) {
    int j = jbase + jj;
    float4 wv[8];
    const float4* wp = (const float4*)(msg_w + (size_t)j * 2048);
    #pragma unroll
    for (int c = 0; c < 8; ++c) wv[c] = wp[c * 64 + lane];
    for (int r = 0; r < 4; ++r) {
      const float4* hp = (const float4*)lin[r];
      float acc = 0.f;
      #pragma unroll
      for (int c = 0; c < 8; ++c) {
        float4 h4 = hp[c * 64 + lane];
        acc += wv[c].x * h4.x + wv[c].y * h4.y + wv[c].z * h4.z + wv[c].w * h4.w;
      }
      #pragma unroll
      for (int off = 32; off; off >>= 1) acc += __shfl_xor(acc, off);
      if (lane == 0) mraw[(size_t)(rt + r) * DIM + j] = acc + msg_b[j];
    }
  }
}

// in-place LN + exact gelu + per-ancestor scalar (+ copy carriers)
__global__ __launch_bounds__(256) void k_ln(SDesc sd, const float* __restrict__ ln_g,
    const float* __restrict__ ln_b, const float* __restrict__ wsc, float* __restrict__ m,
    int NMAIN, int NC,
    const float4* __restrict__ csrc, float4* __restrict__ cdst, int cstart, int cn) {
  int p = blockIdx.x;
  if (p >= NMAIN) { do_copy(csrc, cdst, p - NMAIN, NC, cstart, cn); return; }
  int row = p;
  int rr = row >> 3;
  int s = 0; while (s + 1 < sd.n && sd.rowbase[s + 1] <= rr) ++s;
  int a = rr - sd.rowbase[s];
  float wmul = wsc[s * 8 + a];
  float* mp = m + (size_t)row * DIM;
  int t = threadIdx.x;
  float4 v = ((float4*)mp)[t];
  float sum = v.x + v.y + v.z + v.w;
  float sq  = v.x * v.x + v.y * v.y + v.z * v.z + v.w * v.w;
  #pragma unroll
  for (int off = 32; off; off >>= 1) { sum += __shfl_xor(sum, off); sq += __shfl_xor(sq, off); }
  __shared__ float s1[4], s2[4];
  int wave = t >> 6, lane = t & 63;
  if (lane == 0) { s1[wave] = sum; s2[wave] = sq; }
  __syncthreads();
  sum = s1[0] + s1[1] + s1[2] + s1[3];
  sq  = s2[0] + s2[1] + s2[2] + s2[3];
  float mu  = sum * (1.f / 1024.f);
  float var = sq * (1.f / 1024.f) - mu * mu;
  float inv = rsqrtf(var + 1e-5f);
  float4 g4 = ((const float4*)ln_g)[t];
  float4 b4 = ((const float4*)ln_b)[t];
  float o[4]  = {v.x, v.y, v.z, v.w};
  float gg[4] = {g4.x, g4.y, g4.z, g4.w};
  float bb[4] = {b4.x, b4.y, b4.z, b4.w};
  #pragma unroll
  for (int i = 0; i < 4; ++i) {
    float u = (o[i] - mu) * inv * gg[i] + bb[i];
    float ge = 0.5f * u * (1.f + erff(u * 0.70710678118654752f));
    o[i] = ge * wmul;
  }
  ((float4*)mp)[t] = make_float4(o[0], o[1], o[2], o[3]);
}

// Gi = mseq @ w_ih.T + b_ih  (240 x 3072, K=1024). 96 j-tiles x Y=30 row-tiles (8 rows).
__global__ __launch_bounds__(256) void k_gi(const float* __restrict__ mseq,
    const float* __restrict__ wih, const float* __restrict__ bih, float* __restrict__ gi,
    int Y, int NC,
    const float4* __restrict__ csrc, float4* __restrict__ cdst, int cstart, int cn) {
  int p = blockIdx.x;
  int NMAIN = 96 * Y;
  if (p >= NMAIN) { do_copy(csrc, cdst, p - NMAIN, NC, cstart, cn); return; }
  int jt = (p & 7) + 8 * (p / (8 * Y));    // 0..95
  int rt = ((p >> 3) % Y) * 8;

  __shared__ float lin[8][1024];
  for (int idx = threadIdx.x; idx < 8 * 256; idx += 256) {
    int r = idx >> 8, c = idx & 255;
    ((float4*)lin[r])[c] = ((const float4*)(mseq + (size_t)(rt + r) * DIM))[c];
  }
  __syncthreads();
  int wave = threadIdx.x >> 6, lane = threadIdx.x & 63;
  int jbase = jt * 32 + wave * 8;
  for (int jj = 0; jj < 8; ++jj) {
    int j = jbase + jj;
    float4 wv[4];
    const float4* wp = (const float4*)(wih + (size_t)j * 1024);
    #pragma unroll
    for (int c = 0; c < 4; ++c) wv[c] = wp[c * 64 + lane];
    for (int r = 0; r < 8; ++r) {
      const float4* hp = (const float4*)lin[r];
      float acc = 0.f;
      #pragma unroll
      for (int c = 0; c < 4; ++c) {
        float4 h4 = hp[c * 64 + lane];
        acc += wv[c].x * h4.x + wv[c].y * h4.y + wv[c].z * h4.z + wv[c].w * h4.w;
      }
      #pragma unroll
      for (int off = 32; off; off >>= 1) acc += __shfl_xor(acc, off);
      if (lane == 0) gi[(size_t)(rt + r) * 3072 + j] = acc + bih[j];
    }
  }
}

// one GRU step. 64 j-tiles x 7 structs; same swizzle every step so each XCD's
// w_hh slice stays L2-hot across all 5 steps.
__global__ __launch_bounds__(256) void k_step(SDesc sd, int t,
    const float* __restrict__ whh, const float* __restrict__ bhh,
    const float* __restrict__ gi, const float* __restrict__ hold, float* __restrict__ hnew,
    int NC, const float4* __restrict__ csrc, float4* __restrict__ cdst, int cstart, int cn) {
  int p = blockIdx.x;
  const int NMAIN = 64 * 7;
  if (p >= NMAIN) { do_copy(csrc, cdst, p - NMAIN, NC, cstart, cn); return; }
  int jt = (p & 7) + 8 * (p / 56);         // 0..63
  int s  = (p >> 3) % 7;
  int t0 = sd.Tmax - sd.A[s];
  if (t < t0) return;
  int a = t - t0;
  __shared__ float lh[8][1024];
  for (int idx = threadIdx.x; idx < 8 * 256; idx += 256) {
    int r = idx >> 8, c = idx & 255;
    ((float4*)lh[r])[c] = ((const float4*)(hold + (size_t)(s * 8 + r) * DIM))[c];
  }
  __syncthreads();
  int wave = threadIdx.x >> 6, lane = threadIdx.x & 63;
  int jbase = jt * 16 + wave * 4;
  for (int jj = 0; jj < 4; ++jj) {
    int j = jbase + jj;
    float4 wr[4], wz[4], wn[4];
    const float4* pr = (const float4*)(whh + (size_t)j * 1024);
    const float4* pz = (const float4*)(whh + (size_t)(1024 + j) * 1024);
    const float4* pn = (const float4*)(whh + (size_t)(2048 + j) * 1024);
    #pragma unroll
    for (int c = 0; c < 4; ++c) { wr[c] = pr[c * 64 + lane]; wz[c] = pz[c * 64 + lane]; wn[c] = pn[c * 64 + lane]; }
    for (int r = 0; r < 8; ++r) {
      const float4* hp = (const float4*)lh[r];
      float ar = 0.f, az = 0.f, an = 0.f;
      #pragma unroll
      for (int c = 0; c < 4; ++c) {
        float4 h4 = hp[c * 64 + lane];
        ar += wr[c].x * h4.x + wr[c].y * h4.y + wr[c].z * h4.z + wr[c].w * h4.w;
        az += wz[c].x * h4.x + wz[c].y * h4.y + wz[c].z * h4.z + wz[c].w * h4.w;
        an += wn[c].x * h4.x + wn[c].y * h4.y + wn[c].z * h4.z + wn[c].w * h4.w;
      }
      #pragma unroll
      for (int off = 32; off; off >>= 1) {
        ar += __shfl_xor(ar, off); az += __shfl_xor(az, off); an += __shfl_xor(an, off);
      }
      if (lane == 0) {
        int srow  = s * 8 + r;
        int girow = (sd.rowbase[s] + a) * 8 + r;
        const float* gp = gi + (size_t)girow * 3072;
        float hr = ar + bhh[j];
        float hz = az + bhh[1024 + j];
        float hn = an + bhh[2048 + j];
        float rg = 1.f / (1.f + expf(-(gp[j] + hr)));
        float zg = 1.f / (1.f + expf(-(gp[1024 + j] + hz)));
        float ng = tanhf(gp[2048 + j] + rg * hn);
        float ho = lh[r][j];
        hnew[(size_t)srow * DIM + j] = (1.f - zg) * ng + zg * ho;
      }
    }
  }
}

// gate + final blended write directly into out rows (runs last; no copy carriers)
__global__ __launch_bounds__(256) void k_gate(SDesc sd, const float* __restrict__ x,
    const float* __restrict__ gw, const float* __restrict__ gb,
    const float* __restrict__ hfin, float* __restrict__ out) {
  int p = blockIdx.x;
  const int Y = 14;
  int jt = (p & 7) + 8 * (p / (8 * Y));    // 0..63
  int rt = ((p >> 3) % Y) * 4;

  __shared__ float lin[4][2048];
  for (int idx = threadIdx.x; idx < 4 * 512; idx += 256) {
    int r = idx >> 9, c = idx & 511;
    int srow = rt + r;
    int s = srow >> 3, b = srow & 7;
    float4 v;
    if (c < 256) v = ((const float4*)(hfin + (size_t)srow * DIM))[c];
    else         v = ((const float4*)(x + ((size_t)b * SEQ + sd.pos[s]) * DIM))[c - 256];
    ((float4*)lin[r])[c] = v;
  }
  __syncthreads();
  int wave = threadIdx.x >> 6, lane = threadIdx.x & 63;
  int jbase = jt * 16 + wave * 4;
  for (int jj = 0; jj < 4; ++jj) {
    int j = jbase + jj;
    float4 wv[8];
    const float4* wp = (const float4*)(gw + (size_t)j * 2048);
    #pragma unroll
    for (int c = 0; c < 8; ++c) wv[c] = wp[c * 64 + lane];
    for (int r = 0; r < 4; ++r) {
      const float4* hp = (const float4*)lin[r];
      float acc = 0.f;
      #pragma unroll
      for (int c = 0; c < 8; ++c) {
        float4 h4 = hp[c * 64 + lane];
        acc += wv[c].x * h4.x + wv[c].y * h4.y + wv[c].z * h4.z + wv[c].w * h4.w;
      }
      #pragma unroll
      for (int off = 32; off; off >>= 1) acc += __shfl_xor(acc, off);
      if (lane == 0) {
        int srow = rt + r; int s = srow >> 3, b = srow & 7;
        float g = 1.f / (1.f + expf(-(acc + gb[j])));
        float agg = lin[r][j], hc = lin[r][1024 + j];
        out[((size_t)b * SEQ + sd.pos[s]) * DIM + j] = g * agg + (1.f - g) * hc;
      }
    }
  }
}

// ---------------- launch ----------------

extern "C" void kernel_launch(void* const* d_in, const int* in_sizes, int n_in,
                              void* d_out, int out_size, void* d_ws, size_t ws_size,
                              hipStream_t stream) {
  const float* x      = (const float*)d_in[0];
  const float* pw_w1  = (const float*)d_in[1];
  const float* pw_b1  = (const float*)d_in[2];
  const float* pw_w2  = (const float*)d_in[3];
  const float* pw_b2  = (const float*)d_in[4];
  const float* msg_w  = (const float*)d_in[5];
  const float* msg_b  = (const float*)d_in[6];
  const float* ln_g   = (const float*)d_in[7];
  const float* ln_b   = (const float*)d_in[8];
  const float* w_ih   = (const float*)d_in[9];
  const float* w_hh   = (const float*)d_in[10];
  const float* b_ih   = (const float*)d_in[11];
  const float* b_hh   = (const float*)d_in[12];
  const float* gate_w = (const float*)d_in[13];
  const float* gate_b = (const float*)d_in[14];
  float* out = (float*)d_out;
  float* ws  = (float*)d_ws;

  SDesc sd = build_structs();   // n=7, Tmax=5, totalRows=30 for S=8192

  const int R = sd.totalRows;          // 30
  float* wout = ws;                    // 64 floats
  float* mseq = wout + 64;
  float* gi   = mseq + (size_t)R * 8 * DIM;
  float* h0   = gi + (size_t)R * 8 * 3072;
  float* h1   = h0 + (size_t)sd.n * 8 * DIM;

  const float4* x4 = (const float4*)x;
  float4* out4 = (float4*)out;
  const int TOTAL4 = (NBATCH * SEQ * DIM) / 4;      // 16,777,216
  const int c_msg = 6000000, c_gi = 5000000, c_step = 950000;
  const int c_ln = TOTAL4 - c_msg - c_gi - 5 * c_step;   // 1,027,216
  const int o_msg = 0;
  const int o_ln  = o_msg + c_msg;
  const int o_gi  = o_ln + c_ln;
  const int o_st  = o_gi + c_gi;

  // prep scalars + zero GRU state
  int nzero4 = (2 * sd.n * 8 * DIM) / 4;            // 28,672
  k_prepzero<<<57, 256, 0, stream>>>(sd, pw_w1, pw_b1, pw_w2, pw_b2, wout, (float4*)h0, nzero4);

  // message matmul (carries 6M f4 of the copy)
  k_msg<<<64 * 60 + 1024, 256, 0, stream>>>(sd, x, msg_w, msg_b, mseq, 60,
                                            1024, x4, out4, o_msg, c_msg);
  // LN/gelu/scale (carries ~1M f4)
  k_ln<<<R * 8 + 512, 256, 0, stream>>>(sd, ln_g, ln_b, wout, mseq,
                                        R * 8, 512, x4, out4, o_ln, c_ln);
  // GRU input precompute (carries 5M f4)
  k_gi<<<96 * 30 + 1024, 256, 0, stream>>>(mseq, w_ih, b_ih, gi, 30,
                                           1024, x4, out4, o_gi, c_gi);

  // GRU recurrence (each step carries 0.95M f4)
  for (int t = 0; t < sd.Tmax; ++t) {
    const float* hr = (t & 1) ? h1 : h0;
    float*       hw = (t & 1) ? h0 : h1;
    k_step<<<64 * 7 + 256, 256, 0, stream>>>(sd, t, w_hh, b_hh, gi, hr, hw,
                                             256, x4, out4, o_st + t * c_step, c_step);
  }
  const float* hfin = (sd.Tmax & 1) ? h1 : h0;

  // gate + final blended rows into out (after all copy slices are done)
  k_gate<<<64 * 14, 256, 0, stream>>>(sd, x, gate_w, gate_b, hfin, out);

  (void)in_sizes; (void)n_in; (void)out_size; (void)ws_size;
}

// Round 3
// 448.583 us; speedup vs baseline: 1.2385x; 1.2385x over previous
//
#include <hip/hip_runtime.h>
#include <math.h>
#include <string.h>

#define SEQ 8192
#define DIM 1024
#define NBATCH 8

typedef float vf4 __attribute__((ext_vector_type(4)));

struct SDesc {
  int n, Tmax, totalRows;
  int pos[8], A[8], rowbase[8];
  int anc[8][8];
  float cnt[8][8];
  int nu;
  int upos[16];        // unique positions (sorted)
  int up_of_s[8];      // u-index of pos[s]
  int s_of_rr[32], a_of_rr[32], ua_of_rr[32];
};

// Host-side faithful reimplementation of _gen_spine/_analyze/_structures,
// including the levels[lvl+1] OVERWRITE semantics of the reference BFS.
static SDesc build_structs() {
  SDesc H{};
  int spine[24];
  int ns = 3; spine[0] = 0; spine[1] = 2; spine[2] = 4;
  for (;;) {
    long nxt = 2L * (spine[ns-1] + spine[ns-2] + spine[ns-3]);
    if (nxt >= SEQ) break;
    spine[ns++] = (int)nxt;
  }
  int rb = 0;
  for (int i = 0; i < ns; ++i) {
    int pos = spine[i];
    if (pos < 3) continue;
    bool visited[24] = {false};
    int levels[12][8]; int lcnt[12];
    for (int l = 0; l < 12; ++l) lcnt[l] = 0;
    levels[0][0] = i; lcnt[0] = 1; visited[i] = true;
    int qidx[64], qlvl[64], qh = 0, qt = 0;
    qidx[qt] = i; qlvl[qt] = 0; qt++;
    int maxd = 0;
    while (qh < qt) {
      int cur = qidx[qh], lvl = qlvl[qh]; qh++;
      if (lvl >= 9) break;
      int newl[8], nn = 0;
      if (cur >= 3) {
        for (int d = 1; d <= 3; ++d) {
          int a = cur - d;
          if (!visited[a]) { visited[a] = true; newl[nn++] = a; qidx[qt] = a; qlvl[qt] = lvl + 1; qt++; }
        }
      }
      if (nn) {
        lcnt[lvl+1] = nn;
        for (int k = 0; k < nn; ++k) levels[lvl+1][k] = newl[k];
        if (lvl + 1 > maxd) maxd = lvl + 1;
      }
    }
    float pcv[24]; bool pcs[24];
    for (int k = 0; k < 24; ++k) { pcv[k] = 0.f; pcs[k] = false; }
    pcv[i] = 1.f; pcs[i] = true;
    for (int lvl = maxd; lvl >= 0; --lvl) {
      for (int nidx = 0; nidx < lcnt[lvl]; ++nidx) {
        int node = levels[lvl][nidx];
        if (node == i) continue;
        if (lvl == maxd) { pcv[node] = 1.f; pcs[node] = true; continue; }
        float c = 0.f;
        for (int cidx = 0; cidx < lcnt[lvl+1]; ++cidx) {
          int ch = levels[lvl+1][cidx];
          if (ch >= 3 && node >= ch - 3 && node <= ch - 1) c += pcs[ch] ? pcv[ch] : 0.f;
        }
        if (lvl != 0) { pcv[node] = c; pcs[node] = true; }
      }
    }
    int A = 0;
    int sidx = H.n;
    for (int lvl = 1; lvl <= maxd; ++lvl) {
      for (int nidx = 0; nidx < lcnt[lvl]; ++nidx) {
        int node = levels[lvl][nidx];
        H.anc[sidx][A] = spine[node];
        H.cnt[sidx][A] = pcs[node] ? pcv[node] : 1.f;
        A++;
      }
    }
    if (A == 0) continue;
    H.pos[sidx] = pos; H.A[sidx] = A; H.rowbase[sidx] = rb; rb += A;
    H.n++;
  }
  H.totalRows = rb;
  H.Tmax = 0;
  for (int s = 0; s < H.n; ++s) if (H.A[s] > H.Tmax) H.Tmax = H.A[s];
  // unique positions
  int vals[128], nv = 0;
  for (int s = 0; s < H.n; ++s) {
    vals[nv++] = H.pos[s];
    for (int a = 0; a < H.A[s]; ++a) vals[nv++] = H.anc[s][a];
  }
  // sort unique
  H.nu = 0;
  for (int i = 0; i < nv; ++i) {
    bool seen = false;
    for (int u = 0; u < H.nu; ++u) if (H.upos[u] == vals[i]) { seen = true; break; }
    if (!seen) H.upos[H.nu++] = vals[i];
  }
  for (int i = 0; i < H.nu; ++i)
    for (int j2 = i + 1; j2 < H.nu; ++j2)
      if (H.upos[j2] < H.upos[i]) { int t = H.upos[i]; H.upos[i] = H.upos[j2]; H.upos[j2] = t; }
  auto uidx = [&](int v) { for (int u = 0; u < H.nu; ++u) if (H.upos[u] == v) return u; return 0; };
  for (int s = 0; s < H.n; ++s) {
    H.up_of_s[s] = uidx(H.pos[s]);
    for (int a = 0; a < H.A[s]; ++a) {
      int rr = H.rowbase[s] + a;
      H.s_of_rr[rr] = s; H.a_of_rr[rr] = a; H.ua_of_rr[rr] = uidx(H.anc[s][a]);
    }
  }
  return H;
}

// ---------------- device helpers ----------------

__device__ __forceinline__ void do_copy(const vf4* __restrict__ src, vf4* __restrict__ dst,
                                        int q, int nc, int start4, int n4) {
  for (int i = q * 256 + threadIdx.x; i < n4; i += nc * 256) {
    vf4 v = __builtin_nontemporal_load(&src[start4 + i]);
    __builtin_nontemporal_store(v, &dst[start4 + i]);
  }
}

__device__ __forceinline__ float wred(float v) {
  #pragma unroll
  for (int off = 32; off; off >>= 1) v += __shfl_xor(v, off);
  return v;
}

__device__ __forceinline__ float dot4(vf4 a, vf4 b) {
  return a.x * b.x + a.y * b.y + a.z * b.z + a.w * b.w;
}

// ---------------- kernels ----------------

// block 0: path-weight MLP scalars; blocks [1,57): zero GRU h; rest: copy
__global__ void k_prepzero(SDesc sd, const float* __restrict__ w1, const float* __restrict__ b1,
                           const float* __restrict__ w2, const float* __restrict__ b2,
                           float* __restrict__ wout, vf4* __restrict__ hz, int nzero4,
                           int NC, const vf4* __restrict__ csrc, vf4* __restrict__ cdst,
                           int cstart, int cn) {
  int p = blockIdx.x;
  if (p >= 57) { do_copy(csrc, cdst, p - 57, NC, cstart, cn); return; }
  if (p == 0) {
    int t = threadIdx.x;
    int s = t >> 3, a = t & 7;
    if (t < 64 && s < sd.n && a < sd.A[s]) {
      float v = sd.cnt[s][a];
      float acc = 0.f;
      for (int i = 0; i < 64; ++i) {
        float h = v * w1[i] + b1[i];
        if (h > 0.f) acc += h * w2[i];
      }
      float o = acc + b2[0];
      float sp = (o > 0.f) ? (o + log1pf(expf(-o))) : log1pf(expf(o));
      wout[s * 8 + a] = sp;
    }
  } else {
    int base = (p - 1) * 512 + threadIdx.x;
    if (base < nzero4)       hz[base]       = (vf4)(0.f);
    if (base + 256 < nzero4) hz[base + 256] = (vf4)(0.f);
  }
}

// T[(u*8+b)][2048]: left half = x_row(u) . msg_w[j][0:1024], right = . msg_w[j][1024:2048]
// 320 main blocks = 64 jc-tiles (32 jc) x 5 row-tiles (16 rows). jc-tile pinned to XCD.
__global__ __launch_bounds__(256, 2) void k_T(SDesc sd, const float* __restrict__ x,
    const float* __restrict__ msg_w, float* __restrict__ T,
    int NC, const vf4* __restrict__ csrc, vf4* __restrict__ cdst, int cstart, int cn) {
  int p = blockIdx.x;
  const int NMAIN = 320;
  if (p >= NMAIN) { do_copy(csrc, cdst, p - NMAIN, NC, cstart, cn); return; }
  int q = p & 63, rt = p >> 6;            // rt 0..4
  int jt = (q & 7) * 8 + (q >> 3);        // 0..63, same jt -> same XCD

  __shared__ float lin[16][1024];
  for (int idx = threadIdx.x; idx < 16 * 256; idx += 256) {
    int r = idx >> 8, c = idx & 255;
    int row = rt * 16 + r; int u = row >> 3, b = row & 7;
    ((vf4*)lin[r])[c] = ((const vf4*)(x + ((size_t)b * SEQ + sd.upos[u]) * DIM))[c];
  }
  __syncthreads();

  int wave = threadIdx.x >> 6, lane = threadIdx.x & 63;
  int jc0 = jt * 32 + wave * 8;
  vf4 wv[8][4];
  #pragma unroll
  for (int jj = 0; jj < 8; ++jj) {
    int jc = jc0 + jj;
    const vf4* wp = (const vf4*)(msg_w + (size_t)(jc & 1023) * 2048 + ((jc >> 10) << 10));
    #pragma unroll
    for (int c = 0; c < 4; ++c) wv[jj][c] = wp[c * 64 + lane];
  }
  for (int r = 0; r < 16; ++r) {
    vf4 a4[4];
    const vf4* hp = (const vf4*)lin[r];
    #pragma unroll
    for (int c = 0; c < 4; ++c) a4[c] = hp[c * 64 + lane];
    float acc[8];
    #pragma unroll
    for (int jj = 0; jj < 8; ++jj) {
      float s0 = 0.f;
      #pragma unroll
      for (int c = 0; c < 4; ++c) s0 += dot4(wv[jj][c], a4[c]);
      acc[jj] = s0;
    }
    #pragma unroll
    for (int jj = 0; jj < 8; ++jj) {
      float s0 = wred(acc[jj]);
      if (lane == 0) T[(size_t)(rt * 16 + r) * 2048 + jc0 + jj] = s0;
    }
  }
}

// assemble m row from T, +msg_b, LN, gelu, * path weight -> mseq
__global__ __launch_bounds__(256) void k_ln(SDesc sd, const float* __restrict__ ln_g,
    const float* __restrict__ ln_b, const float* __restrict__ msg_b,
    const float* __restrict__ wsc, const float* __restrict__ T, float* __restrict__ mseq,
    int M, int NC, const vf4* __restrict__ csrc, vf4* __restrict__ cdst, int cstart, int cn) {
  int p = blockIdx.x;
  if (p >= M) { do_copy(csrc, cdst, p - M, NC, cstart, cn); return; }
  int rr = p >> 3, b = p & 7;
  int s = sd.s_of_rr[rr], a = sd.a_of_rr[rr];
  int ua = sd.ua_of_rr[rr], up = sd.up_of_s[s];
  float wmul = wsc[s * 8 + a];
  const vf4* Tl = (const vf4*)(T + ((size_t)ua * 8 + b) * 2048);
  const vf4* Tr = (const vf4*)(T + ((size_t)up * 8 + b) * 2048 + 1024);
  const vf4* mb = (const vf4*)msg_b;
  int t = threadIdx.x;
  vf4 vl = Tl[t], vr = Tr[t], vb = mb[t];
  vf4 v; v.x = vl.x + vr.x + vb.x; v.y = vl.y + vr.y + vb.y;
  v.z = vl.z + vr.z + vb.z; v.w = vl.w + vr.w + vb.w;
  float sum = v.x + v.y + v.z + v.w;
  float sq  = v.x * v.x + v.y * v.y + v.z * v.z + v.w * v.w;
  #pragma unroll
  for (int off = 32; off; off >>= 1) { sum += __shfl_xor(sum, off); sq += __shfl_xor(sq, off); }
  __shared__ float s1[4], s2[4];
  int wave = t >> 6, lane = t & 63;
  if (lane == 0) { s1[wave] = sum; s2[wave] = sq; }
  __syncthreads();
  sum = s1[0] + s1[1] + s1[2] + s1[3];
  sq  = s2[0] + s2[1] + s2[2] + s2[3];
  float mu  = sum * (1.f / 1024.f);
  float var = sq * (1.f / 1024.f) - mu * mu;
  float inv = rsqrtf(var + 1e-5f);
  vf4 g4 = ((const vf4*)ln_g)[t];
  vf4 b4 = ((const vf4*)ln_b)[t];
  float o[4]  = {v.x, v.y, v.z, v.w};
  float gg[4] = {g4.x, g4.y, g4.z, g4.w};
  float bb[4] = {b4.x, b4.y, b4.z, b4.w};
  #pragma unroll
  for (int i = 0; i < 4; ++i) {
    float u = (o[i] - mu) * inv * gg[i] + bb[i];
    float ge = 0.5f * u * (1.f + erff(u * 0.70710678118654752f));
    o[i] = ge * wmul;
  }
  vf4 ov; ov.x = o[0]; ov.y = o[1]; ov.z = o[2]; ov.w = o[3];
  ((vf4*)(mseq + (size_t)p * DIM))[t] = ov;
}

// gi = mseq @ w_ih.T + b_ih.  M x 3072, K=1024.
// main blocks = 96 j-tiles (32 j) x NRT row-tiles (16 rows); j-tile pinned to XCD.
__global__ __launch_bounds__(256, 2) void k_gi(const float* __restrict__ mseq,
    const float* __restrict__ wih, const float* __restrict__ bih, float* __restrict__ gi,
    int M, int NRT, int NC,
    const vf4* __restrict__ csrc, vf4* __restrict__ cdst, int cstart, int cn) {
  int p = blockIdx.x;
  int NMAIN = 96 * NRT;
  if (p >= NMAIN) { do_copy(csrc, cdst, p - NMAIN, NC, cstart, cn); return; }
  int q = p % 96, rt = p / 96;
  int jt = (q & 7) * 12 + (q >> 3);       // 0..95

  __shared__ float lin[16][1024];
  for (int idx = threadIdx.x; idx < 16 * 256; idx += 256) {
    int r = idx >> 8, c = idx & 255;
    int row = rt * 16 + r;
    if (row < M) ((vf4*)lin[r])[c] = ((const vf4*)(mseq + (size_t)row * DIM))[c];
  }
  __syncthreads();

  int wave = threadIdx.x >> 6, lane = threadIdx.x & 63;
  int j0 = jt * 32 + wave * 8;
  vf4 wv[8][4];
  #pragma unroll
  for (int jj = 0; jj < 8; ++jj) {
    const vf4* wp = (const vf4*)(wih + (size_t)(j0 + jj) * 1024);
    #pragma unroll
    for (int c = 0; c < 4; ++c) wv[jj][c] = wp[c * 64 + lane];
  }
  int rmax = M - rt * 16; if (rmax > 16) rmax = 16;
  for (int r = 0; r < rmax; ++r) {
    vf4 a4[4];
    const vf4* hp = (const vf4*)lin[r];
    #pragma unroll
    for (int c = 0; c < 4; ++c) a4[c] = hp[c * 64 + lane];
    float acc[8];
    #pragma unroll
    for (int jj = 0; jj < 8; ++jj) {
      float s0 = 0.f;
      #pragma unroll
      for (int c = 0; c < 4; ++c) s0 += dot4(wv[jj][c], a4[c]);
      acc[jj] = s0;
    }
    #pragma unroll
    for (int jj = 0; jj < 8; ++jj) {
      float s0 = wred(acc[jj]);
      if (lane == 0) gi[(size_t)(rt * 16 + r) * 3072 + j0 + jj] = s0 + bih[j0 + jj];
    }
  }
}

// one GRU step: 7 structs x 128 j-tiles (8 j). j-tile pinned to XCD across structs & steps.
__global__ __launch_bounds__(256, 2) void k_step(SDesc sd, int t,
    const float* __restrict__ whh, const float* __restrict__ bhh,
    const float* __restrict__ gi, const float* __restrict__ hold, float* __restrict__ hnew,
    int NC, const vf4* __restrict__ csrc, vf4* __restrict__ cdst, int cstart, int cn) {
  int p = blockIdx.x;
  const int NMAIN = 7 * 128;
  if (p >= NMAIN) { do_copy(csrc, cdst, p - NMAIN, NC, cstart, cn); return; }
  int q = p & 127, s = p >> 7;
  int jt = (q & 7) * 16 + (q >> 3);       // 0..127
  int t0 = sd.Tmax - sd.A[s];
  if (t < t0) return;
  int a = t - t0;

  __shared__ float lh[8][1024];
  for (int idx = threadIdx.x; idx < 8 * 256; idx += 256) {
    int r = idx >> 8, c = idx & 255;
    ((vf4*)lh[r])[c] = ((const vf4*)(hold + (size_t)(s * 8 + r) * DIM))[c];
  }
  __syncthreads();

  int wave = threadIdx.x >> 6, lane = threadIdx.x & 63;
  int jbase = jt * 8 + wave * 2;
  vf4 w[2][3][4];
  #pragma unroll
  for (int jj = 0; jj < 2; ++jj) {
    int j = jbase + jj;
    #pragma unroll
    for (int g = 0; g < 3; ++g) {
      const vf4* wp = (const vf4*)(whh + (size_t)(g * 1024 + j) * 1024);
      #pragma unroll
      for (int c = 0; c < 4; ++c) w[jj][g][c] = wp[c * 64 + lane];
    }
  }
  for (int r = 0; r < 8; ++r) {
    vf4 a4[4];
    const vf4* hp = (const vf4*)lh[r];
    #pragma unroll
    for (int c = 0; c < 4; ++c) a4[c] = hp[c * 64 + lane];
    #pragma unroll
    for (int jj = 0; jj < 2; ++jj) {
      float ar = 0.f, az = 0.f, an = 0.f;
      #pragma unroll
      for (int c = 0; c < 4; ++c) {
        ar += dot4(w[jj][0][c], a4[c]);
        az += dot4(w[jj][1][c], a4[c]);
        an += dot4(w[jj][2][c], a4[c]);
      }
      ar = wred(ar); az = wred(az); an = wred(an);
      if (lane == 0) {
        int j = jbase + jj;
        int girow = (sd.rowbase[s] + a) * 8 + r;
        const float* gp = gi + (size_t)girow * 3072;
        float hr = ar + bhh[j];
        float hz = az + bhh[1024 + j];
        float hn = an + bhh[2048 + j];
        float rg = 1.f / (1.f + expf(-(gp[j] + hr)));
        float zg = 1.f / (1.f + expf(-(gp[1024 + j] + hz)));
        float ng = tanhf(gp[2048 + j] + rg * hn);
        float ho = lh[r][j];
        hnew[(size_t)(s * 8 + r) * DIM + j] = (1.f - zg) * ng + zg * ho;
      }
    }
  }
}

// gate + final blend into out pos rows. 448 blocks = 64 j-tiles (16 j) x 7 row-tiles (8 rows).
__global__ __launch_bounds__(256, 2) void k_gate(SDesc sd, const float* __restrict__ x,
    const float* __restrict__ gw, const float* __restrict__ gb,
    const float* __restrict__ hfin, float* __restrict__ out) {
  int p = blockIdx.x;
  int q = p & 63, rt = p >> 6;            // rt 0..6
  int jt = (q & 7) * 8 + (q >> 3);        // 0..63

  __shared__ float lina[8][1024];
  __shared__ float linx[8][1024];
  for (int idx = threadIdx.x; idx < 8 * 256; idx += 256) {
    int r = idx >> 8, c = idx & 255;
    int row = rt * 8 + r; int s = row >> 3, b = row & 7;
    ((vf4*)lina[r])[c] = ((const vf4*)(hfin + (size_t)(s * 8 + b) * DIM))[c];
    ((vf4*)linx[r])[c] = ((const vf4*)(x + ((size_t)b * SEQ + sd.pos[s]) * DIM))[c];
  }
  __syncthreads();

  int wave = threadIdx.x >> 6, lane = threadIdx.x & 63;
  int j0 = jt * 16 + wave * 4;
  vf4 wL[4][4], wR[4][4];
  #pragma unroll
  for (int jj = 0; jj < 4; ++jj) {
    const vf4* wp = (const vf4*)(gw + (size_t)(j0 + jj) * 2048);
    #pragma unroll
    for (int c = 0; c < 4; ++c) { wL[jj][c] = wp[c * 64 + lane]; wR[jj][c] = wp[256 + c * 64 + lane]; }
  }
  for (int r = 0; r < 8; ++r) {
    vf4 a4[4], x4[4];
    const vf4* ap = (const vf4*)lina[r];
    const vf4* xp = (const vf4*)linx[r];
    #pragma unroll
    for (int c = 0; c < 4; ++c) { a4[c] = ap[c * 64 + lane]; x4[c] = xp[c * 64 + lane]; }
    float acc[4];
    #pragma unroll
    for (int jj = 0; jj < 4; ++jj) {
      float s0 = 0.f;
      #pragma unroll
      for (int c = 0; c < 4; ++c) s0 += dot4(wL[jj][c], a4[c]) + dot4(wR[jj][c], x4[c]);
      acc[jj] = s0;
    }
    #pragma unroll
    for (int jj = 0; jj < 4; ++jj) {
      float s0 = wred(acc[jj]);
      if (lane == 0) {
        int j = j0 + jj;
        int row = rt * 8 + r; int s = row >> 3, b = row & 7;
        float g = 1.f / (1.f + expf(-(s0 + gb[j])));
        float agg = lina[r][j], hc = linx[r][j];
        out[((size_t)b * SEQ + sd.pos[s]) * DIM + j] = g * agg + (1.f - g) * hc;
      }
    }
  }
}

// ---------------- launch ----------------

extern "C" void kernel_launch(void* const* d_in, const int* in_sizes, int n_in,
                              void* d_out, int out_size, void* d_ws, size_t ws_size,
                              hipStream_t stream) {
  const float* x      = (const float*)d_in[0];
  const float* pw_w1  = (const float*)d_in[1];
  const float* pw_b1  = (const float*)d_in[2];
  const float* pw_w2  = (const float*)d_in[3];
  const float* pw_b2  = (const float*)d_in[4];
  const float* msg_w  = (const float*)d_in[5];
  const float* msg_b  = (const float*)d_in[6];
  const float* ln_g   = (const float*)d_in[7];
  const float* ln_b   = (const float*)d_in[8];
  const float* w_ih   = (const float*)d_in[9];
  const float* w_hh   = (const float*)d_in[10];
  const float* b_ih   = (const float*)d_in[11];
  const float* b_hh   = (const float*)d_in[12];
  const float* gate_w = (const float*)d_in[13];
  const float* gate_b = (const float*)d_in[14];
  float* out = (float*)d_out;
  float* ws  = (float*)d_ws;

  SDesc sd = build_structs();          // n=7, Tmax=5 for S=8192
  const int R = sd.totalRows;
  const int M = R * 8;                 // message rows
  const int NRT = (M + 15) / 16;

  float* wout = ws;                                    // 64
  float* T    = wout + 64;                             // 80*2048
  float* mseq = T + (size_t)sd.nu * 8 * 2048;          // M*1024 (reserve 240)
  float* gi   = mseq + (size_t)240 * DIM;              // M*3072 (reserve 240)
  float* h0   = gi + (size_t)240 * 3072;               // 56*1024
  float* h1   = h0 + (size_t)sd.n * 8 * DIM;

  const vf4* x4 = (const vf4*)x;
  vf4* out4 = (vf4*)out;
  const int TOTAL4 = (NBATCH * SEQ * DIM) / 4;         // 16,777,216
  const int c_prep = 1977216, c_T = 2900000, c_ln = 2400000, c_gi = 4000000, c_step = 1100000;
  const int o_prep = 0;
  const int o_T    = o_prep + c_prep;
  const int o_ln   = o_T + c_T;
  const int o_gi   = o_ln + c_ln;
  const int o_st   = o_gi + c_gi;                      // + t*c_step; ends at TOTAL4

  int nzero4 = (2 * sd.n * 8 * DIM) / 4;               // 28,672

  k_prepzero<<<57 + 1024, 256, 0, stream>>>(sd, pw_w1, pw_b1, pw_w2, pw_b2, wout,
                                            (vf4*)h0, nzero4, 1024, x4, out4, o_prep, c_prep);

  k_T<<<320 + 1024, 256, 0, stream>>>(sd, x, msg_w, T, 1024, x4, out4, o_T, c_T);

  k_ln<<<M + 1024, 256, 0, stream>>>(sd, ln_g, ln_b, msg_b, wout, T, mseq,
                                     M, 1024, x4, out4, o_ln, c_ln);

  k_gi<<<96 * NRT + 1536, 256, 0, stream>>>(mseq, w_ih, b_ih, gi, M, NRT,
                                            1536, x4, out4, o_gi, c_gi);

  for (int t = 0; t < sd.Tmax; ++t) {
    const float* hr = (t & 1) ? h1 : h0;
    float*       hw = (t & 1) ? h0 : h1;
    k_step<<<7 * 128 + 512, 256, 0, stream>>>(sd, t, w_hh, b_hh, gi, hr, hw,
                                              512, x4, out4, o_st + t * c_step, c_step);
  }
  const float* hfin = (sd.Tmax & 1) ? h1 : h0;

  k_gate<<<64 * 7, 256, 0, stream>>>(sd, x, gate_w, gate_b, hfin, out);

  (void)in_sizes; (void)n_in; (void)out_size; (void)ws_size;
}

// Round 4
// 301.488 us; speedup vs baseline: 1.8428x; 1.4879x over previous
//
#include <hip/hip_runtime.h>
#include <math.h>
#include <string.h>

#define SEQ 8192
#define DIM 1024
#define NBATCH 8

typedef float vf4 __attribute__((ext_vector_type(4)));

struct SDesc {
  int n, Tmax, totalRows;
  int pos[8], A[8], rowbase[8];
  int anc[8][8];
  float cnt[8][8];
  int nu;
  int upos[16];
  int up_of_s[8];
  int s_of_rr[32], a_of_rr[32], ua_of_rr[32];
};

// Host-side faithful reimplementation of _gen_spine/_analyze/_structures,
// including the levels[lvl+1] OVERWRITE semantics of the reference BFS.
static SDesc build_structs() {
  SDesc H{};
  int spine[24];
  int ns = 3; spine[0] = 0; spine[1] = 2; spine[2] = 4;
  for (;;) {
    long nxt = 2L * (spine[ns-1] + spine[ns-2] + spine[ns-3]);
    if (nxt >= SEQ) break;
    spine[ns++] = (int)nxt;
  }
  int rb = 0;
  for (int i = 0; i < ns; ++i) {
    int pos = spine[i];
    if (pos < 3) continue;
    bool visited[24] = {false};
    int levels[12][8]; int lcnt[12];
    for (int l = 0; l < 12; ++l) lcnt[l] = 0;
    levels[0][0] = i; lcnt[0] = 1; visited[i] = true;
    int qidx[64], qlvl[64], qh = 0, qt = 0;
    qidx[qt] = i; qlvl[qt] = 0; qt++;
    int maxd = 0;
    while (qh < qt) {
      int cur = qidx[qh], lvl = qlvl[qh]; qh++;
      if (lvl >= 9) break;
      int newl[8], nn = 0;
      if (cur >= 3) {
        for (int d = 1; d <= 3; ++d) {
          int a = cur - d;
          if (!visited[a]) { visited[a] = true; newl[nn++] = a; qidx[qt] = a; qlvl[qt] = lvl + 1; qt++; }
        }
      }
      if (nn) {
        lcnt[lvl+1] = nn;
        for (int k = 0; k < nn; ++k) levels[lvl+1][k] = newl[k];
        if (lvl + 1 > maxd) maxd = lvl + 1;
      }
    }
    float pcv[24]; bool pcs[24];
    for (int k = 0; k < 24; ++k) { pcv[k] = 0.f; pcs[k] = false; }
    pcv[i] = 1.f; pcs[i] = true;
    for (int lvl = maxd; lvl >= 0; --lvl) {
      for (int nidx = 0; nidx < lcnt[lvl]; ++nidx) {
        int node = levels[lvl][nidx];
        if (node == i) continue;
        if (lvl == maxd) { pcv[node] = 1.f; pcs[node] = true; continue; }
        float c = 0.f;
        for (int cidx = 0; cidx < lcnt[lvl+1]; ++cidx) {
          int ch = levels[lvl+1][cidx];
          if (ch >= 3 && node >= ch - 3 && node <= ch - 1) c += pcs[ch] ? pcv[ch] : 0.f;
        }
        if (lvl != 0) { pcv[node] = c; pcs[node] = true; }
      }
    }
    int A = 0;
    int sidx = H.n;
    for (int lvl = 1; lvl <= maxd; ++lvl) {
      for (int nidx = 0; nidx < lcnt[lvl]; ++nidx) {
        int node = levels[lvl][nidx];
        H.anc[sidx][A] = spine[node];
        H.cnt[sidx][A] = pcs[node] ? pcv[node] : 1.f;
        A++;
      }
    }
    if (A == 0) continue;
    H.pos[sidx] = pos; H.A[sidx] = A; H.rowbase[sidx] = rb; rb += A;
    H.n++;
  }
  H.totalRows = rb;
  H.Tmax = 0;
  for (int s = 0; s < H.n; ++s) if (H.A[s] > H.Tmax) H.Tmax = H.A[s];
  int vals[128], nv = 0;
  for (int s = 0; s < H.n; ++s) {
    vals[nv++] = H.pos[s];
    for (int a = 0; a < H.A[s]; ++a) vals[nv++] = H.anc[s][a];
  }
  H.nu = 0;
  for (int i = 0; i < nv; ++i) {
    bool seen = false;
    for (int u = 0; u < H.nu; ++u) if (H.upos[u] == vals[i]) { seen = true; break; }
    if (!seen) H.upos[H.nu++] = vals[i];
  }
  for (int i = 0; i < H.nu; ++i)
    for (int j2 = i + 1; j2 < H.nu; ++j2)
      if (H.upos[j2] < H.upos[i]) { int t = H.upos[i]; H.upos[i] = H.upos[j2]; H.upos[j2] = t; }
  auto uidx = [&](int v) { for (int u = 0; u < H.nu; ++u) if (H.upos[u] == v) return u; return 0; };
  for (int s = 0; s < H.n; ++s) {
    H.up_of_s[s] = uidx(H.pos[s]);
    for (int a = 0; a < H.A[s]; ++a) {
      int rr = H.rowbase[s] + a;
      H.s_of_rr[rr] = s; H.a_of_rr[rr] = a; H.ua_of_rr[rr] = uidx(H.anc[s][a]);
    }
  }
  return H;
}

// ---------------- device helpers ----------------

__device__ __forceinline__ void do_copy(const vf4* __restrict__ src, vf4* __restrict__ dst,
                                        int q, int nc, int start4, int n4) {
  for (int i = q * 256 + threadIdx.x; i < n4; i += nc * 256) {
    vf4 v = __builtin_nontemporal_load(&src[start4 + i]);
    __builtin_nontemporal_store(v, &dst[start4 + i]);
  }
}

__device__ __forceinline__ float wred(float v) {
  #pragma unroll
  for (int off = 32; off; off >>= 1) v += __shfl_xor(v, off);
  return v;
}

__device__ __forceinline__ float dot4(vf4 a, vf4 b) {
  return a.x * b.x + a.y * b.y + a.z * b.z + a.w * b.w;
}

// ---------------- kernels ----------------

// block 0: path-weight MLP scalars; blocks [1,57): zero GRU h; rest: copy
__global__ void k_prepzero(SDesc sd, const float* __restrict__ w1, const float* __restrict__ b1,
                           const float* __restrict__ w2, const float* __restrict__ b2,
                           float* __restrict__ wout, vf4* __restrict__ hz, int nzero4,
                           int NC, const vf4* __restrict__ csrc, vf4* __restrict__ cdst,
                           int cstart, int cn) {
  int p = blockIdx.x;
  if (p >= 57) { do_copy(csrc, cdst, p - 57, NC, cstart, cn); return; }
  if (p == 0) {
    int t = threadIdx.x;
    int s = t >> 3, a = t & 7;
    if (t < 64 && s < sd.n && a < sd.A[s]) {
      float v = sd.cnt[s][a];
      float acc = 0.f;
      for (int i = 0; i < 64; ++i) {
        float h = v * w1[i] + b1[i];
        if (h > 0.f) acc += h * w2[i];
      }
      float o = acc + b2[0];
      float sp = (o > 0.f) ? (o + log1pf(expf(-o))) : log1pf(expf(o));
      wout[s * 8 + a] = sp;
    }
  } else {
    int base = (p - 1) * 512 + threadIdx.x;
    if (base < nzero4)       hz[base]       = (vf4)(0.f);
    if (base + 256 < nzero4) hz[base + 256] = (vf4)(0.f);
  }
}

// T[(u*8+b)][2048]. Main: 128 j-tiles(16 jc) x 10 row-tiles(8 rows) = 1280 blocks.
// Per wave: 4 jc, 16 vf4 of weights in regs; rows direct from global (L2).
__global__ __launch_bounds__(256, 2) void k_T(SDesc sd, const float* __restrict__ x,
    const float* __restrict__ msg_w, float* __restrict__ T,
    int NC, const vf4* __restrict__ csrc, vf4* __restrict__ cdst, int cstart, int cn) {
  int p = blockIdx.x;
  const int NMAIN = 1280;
  if (p >= NMAIN) { do_copy(csrc, cdst, p - NMAIN, NC, cstart, cn); return; }
  int q = p % 128, rt = p / 128;          // rt 0..9
  int jt = (q & 7) * 16 + (q >> 3);       // 0..127, XCD-pinned

  int wave = threadIdx.x >> 6, lane = threadIdx.x & 63;
  int jc0 = jt * 16 + wave * 4;
  const vf4* mw4 = (const vf4*)msg_w;
  // weight bases for 4 jc (left/right half select folded into address)
  size_t b0 = (size_t)((jc0 + 0) & 1023) * 512 + (((jc0 + 0) >> 10) << 8);
  size_t b1 = (size_t)((jc0 + 1) & 1023) * 512 + (((jc0 + 1) >> 10) << 8);
  size_t b2 = (size_t)((jc0 + 2) & 1023) * 512 + (((jc0 + 2) >> 10) << 8);
  size_t b3 = (size_t)((jc0 + 3) & 1023) * 512 + (((jc0 + 3) >> 10) << 8);
  vf4 w0[4], w1[4], w2[4], w3[4];
  #pragma unroll
  for (int c = 0; c < 4; ++c) {
    w0[c] = mw4[b0 + c * 64 + lane];
    w1[c] = mw4[b1 + c * 64 + lane];
    w2[c] = mw4[b2 + c * 64 + lane];
    w3[c] = mw4[b3 + c * 64 + lane];
  }
  const vf4* x4 = (const vf4*)x;
  #pragma unroll 2
  for (int r = 0; r < 8; ++r) {
    int row = rt * 8 + r; int u = row >> 3, b = row & 7;
    size_t rb4 = ((size_t)b * SEQ + sd.upos[u]) * 256;
    vf4 a0 = x4[rb4 + 0 * 64 + lane], a1 = x4[rb4 + 1 * 64 + lane];
    vf4 a2 = x4[rb4 + 2 * 64 + lane], a3 = x4[rb4 + 3 * 64 + lane];
    float s0 = dot4(w0[0], a0) + dot4(w0[1], a1) + dot4(w0[2], a2) + dot4(w0[3], a3);
    float s1 = dot4(w1[0], a0) + dot4(w1[1], a1) + dot4(w1[2], a2) + dot4(w1[3], a3);
    float s2 = dot4(w2[0], a0) + dot4(w2[1], a1) + dot4(w2[2], a2) + dot4(w2[3], a3);
    float s3 = dot4(w3[0], a0) + dot4(w3[1], a1) + dot4(w3[2], a2) + dot4(w3[3], a3);
    s0 = wred(s0); s1 = wred(s1); s2 = wred(s2); s3 = wred(s3);
    if (lane == 0) {
      float* tp = T + (size_t)row * 2048 + jc0;
      tp[0] = s0; tp[1] = s1; tp[2] = s2; tp[3] = s3;
    }
  }
}

// assemble m row from T, +msg_b, LN, gelu, * path weight -> mseq
__global__ __launch_bounds__(256) void k_ln(SDesc sd, const float* __restrict__ ln_g,
    const float* __restrict__ ln_b, const float* __restrict__ msg_b,
    const float* __restrict__ wsc, const float* __restrict__ T, float* __restrict__ mseq,
    int M, int NC, const vf4* __restrict__ csrc, vf4* __restrict__ cdst, int cstart, int cn) {
  int p = blockIdx.x;
  if (p >= M) { do_copy(csrc, cdst, p - M, NC, cstart, cn); return; }
  int rr = p >> 3, b = p & 7;
  int s = sd.s_of_rr[rr], a = sd.a_of_rr[rr];
  int ua = sd.ua_of_rr[rr], up = sd.up_of_s[s];
  float wmul = wsc[s * 8 + a];
  const vf4* Tl = (const vf4*)(T + ((size_t)ua * 8 + b) * 2048);
  const vf4* Tr = (const vf4*)(T + ((size_t)up * 8 + b) * 2048 + 1024);
  const vf4* mb = (const vf4*)msg_b;
  int t = threadIdx.x;
  vf4 vl = Tl[t], vr = Tr[t], vb = mb[t];
  vf4 v; v.x = vl.x + vr.x + vb.x; v.y = vl.y + vr.y + vb.y;
  v.z = vl.z + vr.z + vb.z; v.w = vl.w + vr.w + vb.w;
  float sum = v.x + v.y + v.z + v.w;
  float sq  = v.x * v.x + v.y * v.y + v.z * v.z + v.w * v.w;
  #pragma unroll
  for (int off = 32; off; off >>= 1) { sum += __shfl_xor(sum, off); sq += __shfl_xor(sq, off); }
  __shared__ float s1[4], s2[4];
  int wave = t >> 6, lane = t & 63;
  if (lane == 0) { s1[wave] = sum; s2[wave] = sq; }
  __syncthreads();
  sum = s1[0] + s1[1] + s1[2] + s1[3];
  sq  = s2[0] + s2[1] + s2[2] + s2[3];
  float mu  = sum * (1.f / 1024.f);
  float var = sq * (1.f / 1024.f) - mu * mu;
  float inv = rsqrtf(var + 1e-5f);
  vf4 g4 = ((const vf4*)ln_g)[t];
  vf4 b4 = ((const vf4*)ln_b)[t];
  float o[4]  = {v.x, v.y, v.z, v.w};
  float gg[4] = {g4.x, g4.y, g4.z, g4.w};
  float bb[4] = {b4.x, b4.y, b4.z, b4.w};
  #pragma unroll
  for (int i = 0; i < 4; ++i) {
    float u = (o[i] - mu) * inv * gg[i] + bb[i];
    float ge = 0.5f * u * (1.f + erff(u * 0.70710678118654752f));
    o[i] = ge * wmul;
  }
  vf4 ov; ov.x = o[0]; ov.y = o[1]; ov.z = o[2]; ov.w = o[3];
  ((vf4*)(mseq + (size_t)p * DIM))[t] = ov;
}

// gi = mseq @ w_ih.T + b_ih. Main: 192 j-tiles(16 j) x 15 row-tiles(16 rows) = 2880.
__global__ __launch_bounds__(256, 2) void k_gi(const float* __restrict__ mseq,
    const float* __restrict__ wih, const float* __restrict__ bih, float* __restrict__ gi,
    int NC, const vf4* __restrict__ csrc, vf4* __restrict__ cdst, int cstart, int cn) {
  int p = blockIdx.x;
  const int NMAIN = 2880;
  if (p >= NMAIN) { do_copy(csrc, cdst, p - NMAIN, NC, cstart, cn); return; }
  int q = p % 192, rt = p / 192;          // rt 0..14
  int jt = (q & 7) * 24 + (q >> 3);       // 0..191, XCD-pinned

  int wave = threadIdx.x >> 6, lane = threadIdx.x & 63;
  int j0 = jt * 16 + wave * 4;
  const vf4* wp4 = (const vf4*)wih;
  vf4 w0[4], w1[4], w2[4], w3[4];
  #pragma unroll
  for (int c = 0; c < 4; ++c) {
    w0[c] = wp4[(size_t)(j0 + 0) * 256 + c * 64 + lane];
    w1[c] = wp4[(size_t)(j0 + 1) * 256 + c * 64 + lane];
    w2[c] = wp4[(size_t)(j0 + 2) * 256 + c * 64 + lane];
    w3[c] = wp4[(size_t)(j0 + 3) * 256 + c * 64 + lane];
  }
  const vf4* m4 = (const vf4*)mseq;
  #pragma unroll 2
  for (int r = 0; r < 16; ++r) {
    int row = rt * 16 + r;
    size_t rb4 = (size_t)row * 256;
    vf4 a0 = m4[rb4 + 0 * 64 + lane], a1 = m4[rb4 + 1 * 64 + lane];
    vf4 a2 = m4[rb4 + 2 * 64 + lane], a3 = m4[rb4 + 3 * 64 + lane];
    float s0 = dot4(w0[0], a0) + dot4(w0[1], a1) + dot4(w0[2], a2) + dot4(w0[3], a3);
    float s1 = dot4(w1[0], a0) + dot4(w1[1], a1) + dot4(w1[2], a2) + dot4(w1[3], a3);
    float s2 = dot4(w2[0], a0) + dot4(w2[1], a1) + dot4(w2[2], a2) + dot4(w2[3], a3);
    float s3 = dot4(w3[0], a0) + dot4(w3[1], a1) + dot4(w3[2], a2) + dot4(w3[3], a3);
    s0 = wred(s0); s1 = wred(s1); s2 = wred(s2); s3 = wred(s3);
    if (lane == 0) {
      float* gp = gi + (size_t)row * 3072 + j0;
      gp[0] = s0 + bih[j0 + 0]; gp[1] = s1 + bih[j0 + 1];
      gp[2] = s2 + bih[j0 + 2]; gp[3] = s3 + bih[j0 + 3];
    }
  }
}

// one GRU step. Main: 7 structs x 256 j-tiles(4 j) = 1792 blocks; 1 j per wave.
__global__ __launch_bounds__(256, 2) void k_step(SDesc sd, int t,
    const float* __restrict__ whh, const float* __restrict__ bhh,
    const float* __restrict__ gi, const float* __restrict__ hold, float* __restrict__ hnew,
    int NC, const vf4* __restrict__ csrc, vf4* __restrict__ cdst, int cstart, int cn) {
  int p = blockIdx.x;
  const int NMAIN = 7 * 256;
  if (p >= NMAIN) { do_copy(csrc, cdst, p - NMAIN, NC, cstart, cn); return; }
  int q = p & 255, s = p >> 8;
  int jt = (q & 7) * 32 + (q >> 3);       // 0..255, XCD-pinned across structs & steps
  int t0 = sd.Tmax - sd.A[s];
  if (t < t0) return;
  int a = t - t0;

  int wave = threadIdx.x >> 6, lane = threadIdx.x & 63;
  int j = jt * 4 + wave;
  const vf4* wp4 = (const vf4*)whh;
  vf4 wr[4], wz[4], wn[4];
  #pragma unroll
  for (int c = 0; c < 4; ++c) {
    wr[c] = wp4[(size_t)j * 256 + c * 64 + lane];
    wz[c] = wp4[(size_t)(1024 + j) * 256 + c * 64 + lane];
    wn[c] = wp4[(size_t)(2048 + j) * 256 + c * 64 + lane];
  }
  const vf4* h4 = (const vf4*)hold;
  #pragma unroll 2
  for (int r = 0; r < 8; ++r) {
    int srow = s * 8 + r;
    size_t rb4 = (size_t)srow * 256;
    vf4 a0 = h4[rb4 + 0 * 64 + lane], a1 = h4[rb4 + 1 * 64 + lane];
    vf4 a2 = h4[rb4 + 2 * 64 + lane], a3 = h4[rb4 + 3 * 64 + lane];
    float ar = dot4(wr[0], a0) + dot4(wr[1], a1) + dot4(wr[2], a2) + dot4(wr[3], a3);
    float az = dot4(wz[0], a0) + dot4(wz[1], a1) + dot4(wz[2], a2) + dot4(wz[3], a3);
    float an = dot4(wn[0], a0) + dot4(wn[1], a1) + dot4(wn[2], a2) + dot4(wn[3], a3);
    ar = wred(ar); az = wred(az); an = wred(an);
    if (lane == 0) {
      int girow = (sd.rowbase[s] + a) * 8 + r;
      const float* gp = gi + (size_t)girow * 3072;
      float hr = ar + bhh[j];
      float hz = az + bhh[1024 + j];
      float hn = an + bhh[2048 + j];
      float rg = 1.f / (1.f + expf(-(gp[j] + hr)));
      float zg = 1.f / (1.f + expf(-(gp[1024 + j] + hz)));
      float ng = tanhf(gp[2048 + j] + rg * hn);
      float ho = hold[(size_t)srow * DIM + j];
      hnew[(size_t)srow * DIM + j] = (1.f - zg) * ng + zg * ho;
    }
  }
}

// gate + final blend. Main: 128 j-tiles(8 j) x 7 row-tiles(8 rows) = 896 blocks; 2 j/wave.
__global__ __launch_bounds__(256, 2) void k_gate(SDesc sd, const float* __restrict__ x,
    const float* __restrict__ gw, const float* __restrict__ gb,
    const float* __restrict__ hfin, float* __restrict__ out) {
  int p = blockIdx.x;
  int q = p % 128, rt = p / 128;          // rt 0..6
  int jt = (q & 7) * 16 + (q >> 3);       // 0..127

  int wave = threadIdx.x >> 6, lane = threadIdx.x & 63;
  int j0 = jt * 8 + wave * 2;
  const vf4* g4p = (const vf4*)gw;
  vf4 wL0[4], wR0[4], wL1[4], wR1[4];
  #pragma unroll
  for (int c = 0; c < 4; ++c) {
    wL0[c] = g4p[(size_t)(j0 + 0) * 512 + c * 64 + lane];
    wR0[c] = g4p[(size_t)(j0 + 0) * 512 + 256 + c * 64 + lane];
    wL1[c] = g4p[(size_t)(j0 + 1) * 512 + c * 64 + lane];
    wR1[c] = g4p[(size_t)(j0 + 1) * 512 + 256 + c * 64 + lane];
  }
  const vf4* h4 = (const vf4*)hfin;
  const vf4* x4 = (const vf4*)x;
  #pragma unroll 2
  for (int r = 0; r < 8; ++r) {
    int row = rt * 8 + r; int s = row >> 3, b = row & 7;
    size_t ab4 = (size_t)row * 256;
    size_t xb4 = ((size_t)b * SEQ + sd.pos[s]) * 256;
    vf4 a0 = h4[ab4 + 0 * 64 + lane], a1 = h4[ab4 + 1 * 64 + lane];
    vf4 a2 = h4[ab4 + 2 * 64 + lane], a3 = h4[ab4 + 3 * 64 + lane];
    vf4 x0 = x4[xb4 + 0 * 64 + lane], x1 = x4[xb4 + 1 * 64 + lane];
    vf4 x2 = x4[xb4 + 2 * 64 + lane], x3 = x4[xb4 + 3 * 64 + lane];
    float s0 = dot4(wL0[0], a0) + dot4(wL0[1], a1) + dot4(wL0[2], a2) + dot4(wL0[3], a3)
             + dot4(wR0[0], x0) + dot4(wR0[1], x1) + dot4(wR0[2], x2) + dot4(wR0[3], x3);
    float s1 = dot4(wL1[0], a0) + dot4(wL1[1], a1) + dot4(wL1[2], a2) + dot4(wL1[3], a3)
             + dot4(wR1[0], x0) + dot4(wR1[1], x1) + dot4(wR1[2], x2) + dot4(wR1[3], x3);
    s0 = wred(s0); s1 = wred(s1);
    if (lane == 0) {
      #pragma unroll
      for (int jj = 0; jj < 2; ++jj) {
        int j = j0 + jj;
        float sv = jj ? s1 : s0;
        float g = 1.f / (1.f + expf(-(sv + gb[j])));
        float agg = hfin[(size_t)row * DIM + j];
        float hc  = x[((size_t)b * SEQ + sd.pos[s]) * DIM + j];
        out[((size_t)b * SEQ + sd.pos[s]) * DIM + j] = g * agg + (1.f - g) * hc;
      }
    }
  }
}

// ---------------- launch ----------------

extern "C" void kernel_launch(void* const* d_in, const int* in_sizes, int n_in,
                              void* d_out, int out_size, void* d_ws, size_t ws_size,
                              hipStream_t stream) {
  const float* x      = (const float*)d_in[0];
  const float* pw_w1  = (const float*)d_in[1];
  const float* pw_b1  = (const float*)d_in[2];
  const float* pw_w2  = (const float*)d_in[3];
  const float* pw_b2  = (const float*)d_in[4];
  const float* msg_w  = (const float*)d_in[5];
  const float* msg_b  = (const float*)d_in[6];
  const float* ln_g   = (const float*)d_in[7];
  const float* ln_b   = (const float*)d_in[8];
  const float* w_ih   = (const float*)d_in[9];
  const float* w_hh   = (const float*)d_in[10];
  const float* b_ih   = (const float*)d_in[11];
  const float* b_hh   = (const float*)d_in[12];
  const float* gate_w = (const float*)d_in[13];
  const float* gate_b = (const float*)d_in[14];
  float* out = (float*)d_out;
  float* ws  = (float*)d_ws;

  SDesc sd = build_structs();          // n=7, Tmax=5, totalRows=30, nu=10 for S=8192
  const int M = sd.totalRows * 8;      // 240

  float* wout = ws;                                    // 64
  float* T    = wout + 64;                             // 80*2048
  float* mseq = T + (size_t)sd.nu * 8 * 2048;          // 240*1024
  float* gi   = mseq + (size_t)240 * DIM;              // 240*3072
  float* h0   = gi + (size_t)240 * 3072;               // 56*1024
  float* h1   = h0 + (size_t)sd.n * 8 * DIM;

  const vf4* x4 = (const vf4*)x;
  vf4* out4 = (vf4*)out;
  const int TOTAL4 = (NBATCH * SEQ * DIM) / 4;         // 16,777,216
  const int c_big = 2200000;                            // prep, T, ln, gi
  const int rem = TOTAL4 - 4 * c_big;                   // 7,977,216
  const int c_step = rem / 5;                           // 1,595,443

  int nzero4 = (2 * sd.n * 8 * DIM) / 4;               // 28,672

  int off = 0;
  k_prepzero<<<57 + 1024, 256, 0, stream>>>(sd, pw_w1, pw_b1, pw_w2, pw_b2, wout,
                                            (vf4*)h0, nzero4, 1024, x4, out4, off, c_big);
  off += c_big;

  k_T<<<1280 + 1024, 256, 0, stream>>>(sd, x, msg_w, T, 1024, x4, out4, off, c_big);
  off += c_big;

  k_ln<<<M + 1024, 256, 0, stream>>>(sd, ln_g, ln_b, msg_b, wout, T, mseq,
                                     M, 1024, x4, out4, off, c_big);
  off += c_big;

  k_gi<<<2880 + 1024, 256, 0, stream>>>(mseq, w_ih, b_ih, gi, 1024, x4, out4, off, c_big);
  off += c_big;

  for (int t = 0; t < sd.Tmax; ++t) {
    const float* hr = (t & 1) ? h1 : h0;
    float*       hw = (t & 1) ? h0 : h1;
    int cnt = (t == sd.Tmax - 1) ? (TOTAL4 - off) : c_step;
    k_step<<<7 * 256 + 768, 256, 0, stream>>>(sd, t, w_hh, b_hh, gi, hr, hw,
                                              768, x4, out4, off, cnt);
    off += cnt;
  }
  const float* hfin = (sd.Tmax & 1) ? h1 : h0;

  k_gate<<<128 * 7, 256, 0, stream>>>(sd, x, gate_w, gate_b, hfin, out);

  (void)in_sizes; (void)n_in; (void)out_size; (void)ws_size;
}

// Round 5
// 266.145 us; speedup vs baseline: 2.0875x; 1.1328x over previous
//
#include <hip/hip_runtime.h>
#include <math.h>
#include <string.h>

#define SEQ 8192
#define DIM 1024
#define NBATCH 8

typedef float vf4 __attribute__((ext_vector_type(4)));

struct SDesc {
  int n, Tmax, totalRows;
  int pos[8], A[8], rowbase[8];
  int anc[8][8];
  float cnt[8][8];
  int nu;
  int upos[16];
  int up_of_s[8];
  int s_of_rr[32], a_of_rr[32], ua_of_rr[32];
};

// Host-side faithful reimplementation of _gen_spine/_analyze/_structures,
// including the levels[lvl+1] OVERWRITE semantics of the reference BFS.
static SDesc build_structs() {
  SDesc H{};
  int spine[24];
  int ns = 3; spine[0] = 0; spine[1] = 2; spine[2] = 4;
  for (;;) {
    long nxt = 2L * (spine[ns-1] + spine[ns-2] + spine[ns-3]);
    if (nxt >= SEQ) break;
    spine[ns++] = (int)nxt;
  }
  int rb = 0;
  for (int i = 0; i < ns; ++i) {
    int pos = spine[i];
    if (pos < 3) continue;
    bool visited[24] = {false};
    int levels[12][8]; int lcnt[12];
    for (int l = 0; l < 12; ++l) lcnt[l] = 0;
    levels[0][0] = i; lcnt[0] = 1; visited[i] = true;
    int qidx[64], qlvl[64], qh = 0, qt = 0;
    qidx[qt] = i; qlvl[qt] = 0; qt++;
    int maxd = 0;
    while (qh < qt) {
      int cur = qidx[qh], lvl = qlvl[qh]; qh++;
      if (lvl >= 9) break;
      int newl[8], nn = 0;
      if (cur >= 3) {
        for (int d = 1; d <= 3; ++d) {
          int a = cur - d;
          if (!visited[a]) { visited[a] = true; newl[nn++] = a; qidx[qt] = a; qlvl[qt] = lvl + 1; qt++; }
        }
      }
      if (nn) {
        lcnt[lvl+1] = nn;
        for (int k = 0; k < nn; ++k) levels[lvl+1][k] = newl[k];
        if (lvl + 1 > maxd) maxd = lvl + 1;
      }
    }
    float pcv[24]; bool pcs[24];
    for (int k = 0; k < 24; ++k) { pcv[k] = 0.f; pcs[k] = false; }
    pcv[i] = 1.f; pcs[i] = true;
    for (int lvl = maxd; lvl >= 0; --lvl) {
      for (int nidx = 0; nidx < lcnt[lvl]; ++nidx) {
        int node = levels[lvl][nidx];
        if (node == i) continue;
        if (lvl == maxd) { pcv[node] = 1.f; pcs[node] = true; continue; }
        float c = 0.f;
        for (int cidx = 0; cidx < lcnt[lvl+1]; ++cidx) {
          int ch = levels[lvl+1][cidx];
          if (ch >= 3 && node >= ch - 3 && node <= ch - 1) c += pcs[ch] ? pcv[ch] : 0.f;
        }
        if (lvl != 0) { pcv[node] = c; pcs[node] = true; }
      }
    }
    int A = 0;
    int sidx = H.n;
    for (int lvl = 1; lvl <= maxd; ++lvl) {
      for (int nidx = 0; nidx < lcnt[lvl]; ++nidx) {
        int node = levels[lvl][nidx];
        H.anc[sidx][A] = spine[node];
        H.cnt[sidx][A] = pcs[node] ? pcv[node] : 1.f;
        A++;
      }
    }
    if (A == 0) continue;
    H.pos[sidx] = pos; H.A[sidx] = A; H.rowbase[sidx] = rb; rb += A;
    H.n++;
  }
  H.totalRows = rb;
  H.Tmax = 0;
  for (int s = 0; s < H.n; ++s) if (H.A[s] > H.Tmax) H.Tmax = H.A[s];
  int vals[128], nv = 0;
  for (int s = 0; s < H.n; ++s) {
    vals[nv++] = H.pos[s];
    for (int a = 0; a < H.A[s]; ++a) vals[nv++] = H.anc[s][a];
  }
  H.nu = 0;
  for (int i = 0; i < nv; ++i) {
    bool seen = false;
    for (int u = 0; u < H.nu; ++u) if (H.upos[u] == vals[i]) { seen = true; break; }
    if (!seen) H.upos[H.nu++] = vals[i];
  }
  for (int i = 0; i < H.nu; ++i)
    for (int j2 = i + 1; j2 < H.nu; ++j2)
      if (H.upos[j2] < H.upos[i]) { int t = H.upos[i]; H.upos[i] = H.upos[j2]; H.upos[j2] = t; }
  auto uidx = [&](int v) { for (int u = 0; u < H.nu; ++u) if (H.upos[u] == v) return u; return 0; };
  for (int s = 0; s < H.n; ++s) {
    H.up_of_s[s] = uidx(H.pos[s]);
    for (int a = 0; a < H.A[s]; ++a) {
      int rr = H.rowbase[s] + a;
      H.s_of_rr[rr] = s; H.a_of_rr[rr] = a; H.ua_of_rr[rr] = uidx(H.anc[s][a]);
    }
  }
  return H;
}

// ---------------- device helpers ----------------

__device__ __forceinline__ void do_copy(const vf4* __restrict__ src, vf4* __restrict__ dst,
                                        int q, int nc, int start4, int n4) {
  for (int i = q * 256 + threadIdx.x; i < n4; i += nc * 256) {
    vf4 v = __builtin_nontemporal_load(&src[start4 + i]);
    __builtin_nontemporal_store(v, &dst[start4 + i]);
  }
}

__device__ __forceinline__ float wred(float v) {
  #pragma unroll
  for (int off = 32; off; off >>= 1) v += __shfl_xor(v, off);
  return v;
}

__device__ __forceinline__ float dot4(vf4 a, vf4 b) {
  return a.x * b.x + a.y * b.y + a.z * b.z + a.w * b.w;
}

// ---------------- kernels ----------------

// T[(u*8+b)][2048]. Main: 128 j-tiles(16 jc) x 10 row-tiles(8 rows) = 1280 blocks.
// Block NMAIN: pw-MLP prep. Blocks > NMAIN: copy.
__global__ __launch_bounds__(256, 4) void k_T(SDesc sd, const float* __restrict__ x,
    const float* __restrict__ msg_w, float* __restrict__ T,
    const float* __restrict__ w1, const float* __restrict__ b1,
    const float* __restrict__ w2, const float* __restrict__ b2, float* __restrict__ wout,
    int NC, const vf4* __restrict__ csrc, vf4* __restrict__ cdst, int cstart, int cn) {
  int p = blockIdx.x;
  const int NMAIN = 1280;
  if (p == NMAIN) {
    int t = threadIdx.x;
    int s = t >> 3, a = t & 7;
    if (t < 64 && s < sd.n && a < sd.A[s]) {
      float v = sd.cnt[s][a];
      float acc = 0.f;
      for (int i = 0; i < 64; ++i) {
        float h = v * w1[i] + b1[i];
        if (h > 0.f) acc += h * w2[i];
      }
      float o = acc + b2[0];
      float sp = (o > 0.f) ? (o + log1pf(expf(-o))) : log1pf(expf(o));
      wout[s * 8 + a] = sp;
    }
    return;
  }
  if (p > NMAIN) { do_copy(csrc, cdst, p - NMAIN - 1, NC, cstart, cn); return; }
  int q = p % 128, rt = p / 128;          // rt 0..9
  int jt = (q & 7) * 16 + (q >> 3);       // 0..127, XCD-pinned

  int wave = threadIdx.x >> 6, lane = threadIdx.x & 63;
  int jc0 = jt * 16 + wave * 4;
  const vf4* mw4 = (const vf4*)msg_w;
  size_t b0 = (size_t)((jc0 + 0) & 1023) * 512 + (((jc0 + 0) >> 10) << 8);
  size_t b1_ = (size_t)((jc0 + 1) & 1023) * 512 + (((jc0 + 1) >> 10) << 8);
  size_t b2_ = (size_t)((jc0 + 2) & 1023) * 512 + (((jc0 + 2) >> 10) << 8);
  size_t b3 = (size_t)((jc0 + 3) & 1023) * 512 + (((jc0 + 3) >> 10) << 8);
  vf4 w0[4], w1v[4], w2v[4], w3[4];
  #pragma unroll
  for (int c = 0; c < 4; ++c) {
    w0[c]  = mw4[b0  + c * 64 + lane];
    w1v[c] = mw4[b1_ + c * 64 + lane];
    w2v[c] = mw4[b2_ + c * 64 + lane];
    w3[c]  = mw4[b3  + c * 64 + lane];
  }
  const vf4* x4 = (const vf4*)x;
  #pragma unroll 2
  for (int r = 0; r < 8; ++r) {
    int row = rt * 8 + r; int u = row >> 3, b = row & 7;
    size_t rb4 = ((size_t)b * SEQ + sd.upos[u]) * 256;
    vf4 a0 = x4[rb4 + 0 * 64 + lane], a1 = x4[rb4 + 1 * 64 + lane];
    vf4 a2 = x4[rb4 + 2 * 64 + lane], a3 = x4[rb4 + 3 * 64 + lane];
    float s0 = dot4(w0[0],  a0) + dot4(w0[1],  a1) + dot4(w0[2],  a2) + dot4(w0[3],  a3);
    float s1 = dot4(w1v[0], a0) + dot4(w1v[1], a1) + dot4(w1v[2], a2) + dot4(w1v[3], a3);
    float s2 = dot4(w2v[0], a0) + dot4(w2v[1], a1) + dot4(w2v[2], a2) + dot4(w2v[3], a3);
    float s3 = dot4(w3[0],  a0) + dot4(w3[1],  a1) + dot4(w3[2],  a2) + dot4(w3[3],  a3);
    s0 = wred(s0); s1 = wred(s1); s2 = wred(s2); s3 = wred(s3);
    if (lane == 0) {
      float* tp = T + (size_t)row * 2048 + jc0;
      tp[0] = s0; tp[1] = s1; tp[2] = s2; tp[3] = s3;
    }
  }
}

// assemble m row from T, +msg_b, LN, gelu, * path weight -> mseq
__global__ __launch_bounds__(256) void k_ln(SDesc sd, const float* __restrict__ ln_g,
    const float* __restrict__ ln_b, const float* __restrict__ msg_b,
    const float* __restrict__ wsc, const float* __restrict__ T, float* __restrict__ mseq,
    int M, int NC, const vf4* __restrict__ csrc, vf4* __restrict__ cdst, int cstart, int cn) {
  int p = blockIdx.x;
  if (p >= M) { do_copy(csrc, cdst, p - M, NC, cstart, cn); return; }
  int rr = p >> 3, b = p & 7;
  int s = sd.s_of_rr[rr], a = sd.a_of_rr[rr];
  int ua = sd.ua_of_rr[rr], up = sd.up_of_s[s];
  float wmul = wsc[s * 8 + a];
  const vf4* Tl = (const vf4*)(T + ((size_t)ua * 8 + b) * 2048);
  const vf4* Tr = (const vf4*)(T + ((size_t)up * 8 + b) * 2048 + 1024);
  const vf4* mb = (const vf4*)msg_b;
  int t = threadIdx.x;
  vf4 vl = Tl[t], vr = Tr[t], vb = mb[t];
  vf4 v; v.x = vl.x + vr.x + vb.x; v.y = vl.y + vr.y + vb.y;
  v.z = vl.z + vr.z + vb.z; v.w = vl.w + vr.w + vb.w;
  float sum = v.x + v.y + v.z + v.w;
  float sq  = v.x * v.x + v.y * v.y + v.z * v.z + v.w * v.w;
  #pragma unroll
  for (int off = 32; off; off >>= 1) { sum += __shfl_xor(sum, off); sq += __shfl_xor(sq, off); }
  __shared__ float s1[4], s2[4];
  int wave = t >> 6, lane = t & 63;
  if (lane == 0) { s1[wave] = sum; s2[wave] = sq; }
  __syncthreads();
  sum = s1[0] + s1[1] + s1[2] + s1[3];
  sq  = s2[0] + s2[1] + s2[2] + s2[3];
  float mu  = sum * (1.f / 1024.f);
  float var = sq * (1.f / 1024.f) - mu * mu;
  float inv = rsqrtf(var + 1e-5f);
  vf4 g4 = ((const vf4*)ln_g)[t];
  vf4 b4 = ((const vf4*)ln_b)[t];
  float o[4]  = {v.x, v.y, v.z, v.w};
  float gg[4] = {g4.x, g4.y, g4.z, g4.w};
  float bb[4] = {b4.x, b4.y, b4.z, b4.w};
  #pragma unroll
  for (int i = 0; i < 4; ++i) {
    float u = (o[i] - mu) * inv * gg[i] + bb[i];
    float ge = 0.5f * u * (1.f + erff(u * 0.70710678118654752f));
    o[i] = ge * wmul;
  }
  vf4 ov; ov.x = o[0]; ov.y = o[1]; ov.z = o[2]; ov.w = o[3];
  ((vf4*)(mseq + (size_t)p * DIM))[t] = ov;
}

// gi = mseq @ w_ih.T + b_ih. Main: 192 j-tiles(16 j) x 15 row-tiles(16 rows) = 2880.
__global__ __launch_bounds__(256, 4) void k_gi(const float* __restrict__ mseq,
    const float* __restrict__ wih, const float* __restrict__ bih, float* __restrict__ gi,
    int NC, const vf4* __restrict__ csrc, vf4* __restrict__ cdst, int cstart, int cn) {
  int p = blockIdx.x;
  const int NMAIN = 2880;
  if (p >= NMAIN) { do_copy(csrc, cdst, p - NMAIN, NC, cstart, cn); return; }
  int q = p % 192, rt = p / 192;          // rt 0..14
  int jt = (q & 7) * 24 + (q >> 3);       // 0..191, XCD-pinned

  int wave = threadIdx.x >> 6, lane = threadIdx.x & 63;
  int j0 = jt * 16 + wave * 4;
  const vf4* wp4 = (const vf4*)wih;
  vf4 w0[4], w1[4], w2[4], w3[4];
  #pragma unroll
  for (int c = 0; c < 4; ++c) {
    w0[c] = wp4[(size_t)(j0 + 0) * 256 + c * 64 + lane];
    w1[c] = wp4[(size_t)(j0 + 1) * 256 + c * 64 + lane];
    w2[c] = wp4[(size_t)(j0 + 2) * 256 + c * 64 + lane];
    w3[c] = wp4[(size_t)(j0 + 3) * 256 + c * 64 + lane];
  }
  const vf4* m4 = (const vf4*)mseq;
  #pragma unroll 2
  for (int r = 0; r < 16; ++r) {
    int row = rt * 16 + r;
    size_t rb4 = (size_t)row * 256;
    vf4 a0 = m4[rb4 + 0 * 64 + lane], a1 = m4[rb4 + 1 * 64 + lane];
    vf4 a2 = m4[rb4 + 2 * 64 + lane], a3 = m4[rb4 + 3 * 64 + lane];
    float s0 = dot4(w0[0], a0) + dot4(w0[1], a1) + dot4(w0[2], a2) + dot4(w0[3], a3);
    float s1 = dot4(w1[0], a0) + dot4(w1[1], a1) + dot4(w1[2], a2) + dot4(w1[3], a3);
    float s2 = dot4(w2[0], a0) + dot4(w2[1], a1) + dot4(w2[2], a2) + dot4(w2[3], a3);
    float s3 = dot4(w3[0], a0) + dot4(w3[1], a1) + dot4(w3[2], a2) + dot4(w3[3], a3);
    s0 = wred(s0); s1 = wred(s1); s2 = wred(s2); s3 = wred(s3);
    if (lane == 0) {
      float* gp = gi + (size_t)row * 3072 + j0;
      gp[0] = s0 + bih[j0 + 0]; gp[1] = s1 + bih[j0 + 1];
      gp[2] = s2 + bih[j0 + 2]; gp[3] = s3 + bih[j0 + 3];
    }
  }
}

// one GRU step. Main: 7 structs x 256 j-tiles(4 j) = 1792 blocks; 1 j per wave.
// a==0 fast path: h==0 -> gh = b_hh; h' = (1-z)*n, elementwise from gi (no matmul).
__global__ __launch_bounds__(256, 4) void k_step(SDesc sd, int t,
    const float* __restrict__ whh, const float* __restrict__ bhh,
    const float* __restrict__ gi, const float* __restrict__ hold, float* __restrict__ hnew,
    int NC, const vf4* __restrict__ csrc, vf4* __restrict__ cdst, int cstart, int cn) {
  int p = blockIdx.x;
  const int NMAIN = 7 * 256;
  if (p >= NMAIN) { do_copy(csrc, cdst, p - NMAIN, NC, cstart, cn); return; }
  int q = p & 255, s = p >> 8;
  int jt = (q & 7) * 32 + (q >> 3);       // 0..255, XCD-pinned across structs & steps
  int t0 = sd.Tmax - sd.A[s];
  if (t < t0) return;
  int a = t - t0;

  int wave = threadIdx.x >> 6, lane = threadIdx.x & 63;
  int j = jt * 4 + wave;
  int girow0 = (sd.rowbase[s] + a) * 8;

  if (a == 0) {
    // elementwise: 8 rows x 1 j per wave; lane r<8 handles row r
    if (lane < 8) {
      int r = lane;
      const float* gp = gi + (size_t)(girow0 + r) * 3072;
      float rg = 1.f / (1.f + expf(-(gp[j] + bhh[j])));
      float zg = 1.f / (1.f + expf(-(gp[1024 + j] + bhh[1024 + j])));
      float ng = tanhf(gp[2048 + j] + rg * bhh[2048 + j]);
      hnew[(size_t)(s * 8 + r) * DIM + j] = (1.f - zg) * ng;
    }
    return;
  }

  const vf4* wp4 = (const vf4*)whh;
  vf4 wr[4], wz[4], wn[4];
  #pragma unroll
  for (int c = 0; c < 4; ++c) {
    wr[c] = wp4[(size_t)j * 256 + c * 64 + lane];
    wz[c] = wp4[(size_t)(1024 + j) * 256 + c * 64 + lane];
    wn[c] = wp4[(size_t)(2048 + j) * 256 + c * 64 + lane];
  }
  float bj_r = bhh[j], bj_z = bhh[1024 + j], bj_n = bhh[2048 + j];
  const vf4* h4 = (const vf4*)hold;
  #pragma unroll 2
  for (int r = 0; r < 8; ++r) {
    int srow = s * 8 + r;
    size_t rb4 = (size_t)srow * 256;
    // uniform-address prefetch of gi values (broadcast load, overlaps matmul)
    const float* gp = gi + (size_t)(girow0 + r) * 3072;
    float gir = gp[j], giz = gp[1024 + j], gin = gp[2048 + j];
    vf4 a0 = h4[rb4 + 0 * 64 + lane], a1 = h4[rb4 + 1 * 64 + lane];
    vf4 a2 = h4[rb4 + 2 * 64 + lane], a3 = h4[rb4 + 3 * 64 + lane];
    float ar = dot4(wr[0], a0) + dot4(wr[1], a1) + dot4(wr[2], a2) + dot4(wr[3], a3);
    float az = dot4(wz[0], a0) + dot4(wz[1], a1) + dot4(wz[2], a2) + dot4(wz[3], a3);
    float an = dot4(wn[0], a0) + dot4(wn[1], a1) + dot4(wn[2], a2) + dot4(wn[3], a3);
    ar = wred(ar); az = wred(az); an = wred(an);
    if (lane == 0) {
      float rg = 1.f / (1.f + expf(-(gir + ar + bj_r)));
      float zg = 1.f / (1.f + expf(-(giz + az + bj_z)));
      float ng = tanhf(gin + rg * (an + bj_n));
      float ho = hold[(size_t)srow * DIM + j];
      hnew[(size_t)srow * DIM + j] = (1.f - zg) * ng + zg * ho;
    }
  }
}

// gate + final blend. Main: 128 j-tiles(8 j) x 7 row-tiles(8 rows) = 896 blocks; 2 j/wave.
__global__ __launch_bounds__(256, 4) void k_gate(SDesc sd, const float* __restrict__ x,
    const float* __restrict__ gw, const float* __restrict__ gb,
    const float* __restrict__ hfin, float* __restrict__ out) {
  int p = blockIdx.x;
  int q = p % 128, rt = p / 128;          // rt 0..6
  int jt = (q & 7) * 16 + (q >> 3);       // 0..127

  int wave = threadIdx.x >> 6, lane = threadIdx.x & 63;
  int j0 = jt * 8 + wave * 2;
  const vf4* g4p = (const vf4*)gw;
  vf4 wL0[4], wR0[4], wL1[4], wR1[4];
  #pragma unroll
  for (int c = 0; c < 4; ++c) {
    wL0[c] = g4p[(size_t)(j0 + 0) * 512 + c * 64 + lane];
    wR0[c] = g4p[(size_t)(j0 + 0) * 512 + 256 + c * 64 + lane];
    wL1[c] = g4p[(size_t)(j0 + 1) * 512 + c * 64 + lane];
    wR1[c] = g4p[(size_t)(j0 + 1) * 512 + 256 + c * 64 + lane];
  }
  const vf4* h4 = (const vf4*)hfin;
  const vf4* x4 = (const vf4*)x;
  #pragma unroll 2
  for (int r = 0; r < 8; ++r) {
    int row = rt * 8 + r; int s = row >> 3, b = row & 7;
    size_t ab4 = (size_t)row * 256;
    size_t xb4 = ((size_t)b * SEQ + sd.pos[s]) * 256;
    vf4 a0 = h4[ab4 + 0 * 64 + lane], a1 = h4[ab4 + 1 * 64 + lane];
    vf4 a2 = h4[ab4 + 2 * 64 + lane], a3 = h4[ab4 + 3 * 64 + lane];
    vf4 x0 = x4[xb4 + 0 * 64 + lane], x1 = x4[xb4 + 1 * 64 + lane];
    vf4 x2 = x4[xb4 + 2 * 64 + lane], x3 = x4[xb4 + 3 * 64 + lane];
    float s0 = dot4(wL0[0], a0) + dot4(wL0[1], a1) + dot4(wL0[2], a2) + dot4(wL0[3], a3)
             + dot4(wR0[0], x0) + dot4(wR0[1], x1) + dot4(wR0[2], x2) + dot4(wR0[3], x3);
    float s1 = dot4(wL1[0], a0) + dot4(wL1[1], a1) + dot4(wL1[2], a2) + dot4(wL1[3], a3)
             + dot4(wR1[0], x0) + dot4(wR1[1], x1) + dot4(wR1[2], x2) + dot4(wR1[3], x3);
    s0 = wred(s0); s1 = wred(s1);
    if (lane == 0) {
      #pragma unroll
      for (int jj = 0; jj < 2; ++jj) {
        int j = j0 + jj;
        float sv = jj ? s1 : s0;
        float g = 1.f / (1.f + expf(-(sv + gb[j])));
        float agg = hfin[(size_t)row * DIM + j];
        float hc  = x[((size_t)b * SEQ + sd.pos[s]) * DIM + j];
        out[((size_t)b * SEQ + sd.pos[s]) * DIM + j] = g * agg + (1.f - g) * hc;
      }
    }
  }
}

// ---------------- launch ----------------

extern "C" void kernel_launch(void* const* d_in, const int* in_sizes, int n_in,
                              void* d_out, int out_size, void* d_ws, size_t ws_size,
                              hipStream_t stream) {
  const float* x      = (const float*)d_in[0];
  const float* pw_w1  = (const float*)d_in[1];
  const float* pw_b1  = (const float*)d_in[2];
  const float* pw_w2  = (const float*)d_in[3];
  const float* pw_b2  = (const float*)d_in[4];
  const float* msg_w  = (const float*)d_in[5];
  const float* msg_b  = (const float*)d_in[6];
  const float* ln_g   = (const float*)d_in[7];
  const float* ln_b   = (const float*)d_in[8];
  const float* w_ih   = (const float*)d_in[9];
  const float* w_hh   = (const float*)d_in[10];
  const float* b_ih   = (const float*)d_in[11];
  const float* b_hh   = (const float*)d_in[12];
  const float* gate_w = (const float*)d_in[13];
  const float* gate_b = (const float*)d_in[14];
  float* out = (float*)d_out;
  float* ws  = (float*)d_ws;

  SDesc sd = build_structs();          // n=7, Tmax=5, totalRows=30, nu=10 for S=8192
  const int M = sd.totalRows * 8;      // 240

  float* wout = ws;                                    // 64
  float* T    = wout + 64;                             // 80*2048
  float* mseq = T + (size_t)sd.nu * 8 * 2048;          // 240*1024
  float* gi   = mseq + (size_t)240 * DIM;              // 240*3072
  float* h0   = gi + (size_t)240 * 3072;               // 56*1024
  float* h1   = h0 + (size_t)sd.n * 8 * DIM;

  const vf4* x4 = (const vf4*)x;
  vf4* out4 = (vf4*)out;
  const int TOTAL4 = (NBATCH * SEQ * DIM) / 4;         // 16,777,216

  // copy budget per kernel (f4 units), balanced to expected main-phase time
  const int c_T  = 2200000;
  const int c_ln = 2400000;
  const int c_gi = 1800000;
  const int c_s0 = 2600000;
  const int c_s  = 1900000;                             // t=1..3
  // t=4 takes remainder

  int off = 0;
  k_T<<<1280 + 1 + 1024, 256, 0, stream>>>(sd, x, msg_w, T,
                                           pw_w1, pw_b1, pw_w2, pw_b2, wout,
                                           1024, x4, out4, off, c_T);
  off += c_T;

  k_ln<<<M + 1280, 256, 0, stream>>>(sd, ln_g, ln_b, msg_b, wout, T, mseq,
                                     M, 1280, x4, out4, off, c_ln);
  off += c_ln;

  k_gi<<<2880 + 1024, 256, 0, stream>>>(mseq, w_ih, b_ih, gi, 1024, x4, out4, off, c_gi);
  off += c_gi;

  for (int t = 0; t < sd.Tmax; ++t) {
    const float* hr = (t & 1) ? h1 : h0;
    float*       hw = (t & 1) ? h0 : h1;
    int cnt = (t == 0) ? c_s0 : (t == sd.Tmax - 1) ? (TOTAL4 - off) : c_s;
    k_step<<<7 * 256 + 1280, 256, 0, stream>>>(sd, t, w_hh, b_hh, gi, hr, hw,
                                               1280, x4, out4, off, cnt);
    off += cnt;
  }
  const float* hfin = (sd.Tmax & 1) ? h1 : h0;

  k_gate<<<128 * 7, 256, 0, stream>>>(sd, x, gate_w, gate_b, hfin, out);

  (void)in_sizes; (void)n_in; (void)out_size; (void)ws_size;
}